// Round 6
// baseline (803.656 us; speedup 1.0000x reference)
//
#include <hip/hip_runtime.h>
#include <hip/hip_bf16.h>

typedef __attribute__((ext_vector_type(8))) short short8;
typedef __attribute__((ext_vector_type(4))) float f32x4;
typedef __attribute__((ext_vector_type(4))) int i32x4;
typedef __attribute__((ext_vector_type(4))) unsigned u32x4;

#define NTOK 512
#define NEXP 16
#define TOPK 4
#define HD   2880
#define ID   2880
#define N1   5760   // 2*I
#define NGRP 90     // 32-value groups per row
#define NKT  45     // HD/64 K-steps

__device__ __forceinline__ unsigned perm(unsigned hi, unsigned lo, unsigned sel) {
  return __builtin_amdgcn_perm(hi, lo, sel);
}

// ---------------- perm-LUT MXFP4 dequant (bit-exact bf16, scale folded) ----------------
__device__ __forceinline__ u32x4 dq_word4(unsigned p, unsigned hbl, unsigned hbh,
                                          unsigned lbl, unsigned lbh) {
  unsigned ph = p >> 4;
  unsigned il = p  & 0x07070707u, sl = p  & 0x08080808u;
  unsigned ih = ph & 0x07070707u, sh = ph & 0x08080808u;
  unsigned hbL = perm(hbh, hbl, il) | (sl << 4);
  unsigned lbL = perm(lbh, lbl, il);
  unsigned hbH = perm(hbh, hbl, ih) | (sh << 4);
  unsigned lbH = perm(lbh, lbl, ih);
  unsigned mL01 = perm(hbL, lbL, 0x05010400u);
  unsigned mL23 = perm(hbL, lbL, 0x07030602u);
  unsigned mH01 = perm(hbH, lbH, 0x05010400u);
  unsigned mH23 = perm(hbH, lbH, 0x07030602u);
  u32x4 w;
  w.x = perm(mH01, mL01, 0x05040100u);
  w.y = perm(mH01, mL01, 0x07060302u);
  w.z = perm(mH23, mL23, 0x05040100u);
  w.w = perm(mH23, mL23, 0x07060302u);
  return w;
}

// one B MFMA fragment: 4 widened nibble-bytes (8 values) + per-lane scale -> short8 bf16
__device__ __forceinline__ short8 dq_frag(i32x4 q, int sc) {
  unsigned m7 = (unsigned)((127 - sc) << 7);          // sc in [118,127]
  unsigned mm = m7 | (m7 << 16);
  unsigned e10 = (0x3F00u - m7) << 16;                // entry0 stays exact 0
  unsigned e32 = 0x3FC03F80u - mm;
  unsigned e54 = 0x40404000u - mm;
  unsigned e76 = 0x40C04080u - mm;
  unsigned hbl = perm(e32, e10, 0x07050301u);
  unsigned hbh = perm(e76, e54, 0x07050301u);
  unsigned lbl = perm(e32, e10, 0x06040200u);
  unsigned lbh = perm(e76, e54, 0x06040200u);
  unsigned pk = (unsigned)q.x | ((unsigned)q.y << 8) |
                ((unsigned)q.z << 16) | ((unsigned)q.w << 24);
  u32x4 w = dq_word4(pk, hbl, hbh, lbl, lbh);
  return __builtin_bit_cast(short8, w);
}

// ---------------- RMSNorm (also zeroes cnt; runs before router on the stream) ----------------
__global__ __launch_bounds__(256)
void rmsnorm_k(const float* __restrict__ x, const float* __restrict__ nsc,
               float* __restrict__ tf, __hip_bfloat16* __restrict__ tb,
               int* __restrict__ cnt)
{
  int t = blockIdx.x;
  if (t == 0 && threadIdx.x < NEXP) cnt[threadIdx.x] = 0;
  const float* xr = x + (size_t)t * HD;
  float s = 0.f;
  for (int i = threadIdx.x; i < HD; i += 256) { float v = xr[i]; s += v * v; }
#pragma unroll
  for (int o = 32; o > 0; o >>= 1) s += __shfl_down(s, o);
  __shared__ float red[4];
  if ((threadIdx.x & 63) == 0) red[threadIdx.x >> 6] = s;
  __syncthreads();
  float tot = red[0] + red[1] + red[2] + red[3];
  float rinv = rsqrtf(tot / (float)HD + 1e-5f);
  for (int i = threadIdx.x; i < HD; i += 256) {
    float v = xr[i] * rinv * nsc[i];
    tf[(size_t)t * HD + i] = v;
    tb[(size_t)t * HD + i] = __float2bfloat16(v);
  }
}

// ---------------- Router ----------------
__global__ __launch_bounds__(256)
void router_k(const float* __restrict__ tf, const float* __restrict__ gw,
              const float* __restrict__ gb, float* __restrict__ wpair,
              int* __restrict__ cnt, int* __restrict__ tok_list, int* __restrict__ pair_list)
{
  int t = blockIdx.x;
  int tid = threadIdx.x;
  int e = tid >> 4, l16 = tid & 15;
  const float* tr = tf + (size_t)t * HD;
  float s = 0.f;
  for (int i = l16; i < HD; i += 16) s += tr[i] * gw[e * HD + i];
#pragma unroll
  for (int o = 1; o < 16; o <<= 1) s += __shfl_xor(s, o);
  __shared__ float logits[NEXP];
  if (l16 == 0) logits[e] = s + gb[e];
  __syncthreads();
  if (tid == 0) {
    float v[NEXP];
#pragma unroll
    for (int i = 0; i < NEXP; ++i) v[i] = logits[i];
    int idx[TOPK]; float val[TOPK];
#pragma unroll
    for (int k = 0; k < TOPK; ++k) {
      int bi = 0; float bv = -1e30f;
      for (int i = 0; i < NEXP; ++i) if (v[i] > bv) { bv = v[i]; bi = i; }
      idx[k] = bi; val[k] = bv; v[bi] = -1e30f;
    }
    float mx = val[0], sum = 0.f, w[TOPK];
#pragma unroll
    for (int k = 0; k < TOPK; ++k) { w[k] = __expf(val[k] - mx); sum += w[k]; }
#pragma unroll
    for (int k = 0; k < TOPK; ++k) {
      float wk = w[k] / sum;
      int ee = idx[k];
      int slot = atomicAdd(&cnt[ee], 1);
      tok_list[ee * NTOK + slot]  = t;
      pair_list[ee * NTOK + slot] = t * TOPK + k;
      wpair[t * TOPK + k] = wk;
    }
  }
}

// ---------------- Grouped GEMM: 1-wave blocks, 64Mx32N tile, LDS-free, barrier-free.
// A (bf16, L2-resident) and B (MXFP4, streamed) load directly into MFMA fragment
// layout; B dequanted in-register via perm-LUT; depth-1 B prefetch; TLP hides rest.
template<int STAGE>
__global__ __launch_bounds__(64)
void moe_gemm(const __hip_bfloat16* __restrict__ Asrc,
              const int* __restrict__ Bblk, const int* __restrict__ Bscl,
              const float* __restrict__ Bbias,
              const int* __restrict__ cnt,
              const int* __restrict__ tok_list, const int* __restrict__ pair_list,
              __hip_bfloat16* __restrict__ h_out, float* __restrict__ o_out)
{
  constexpr int NDIM = (STAGE == 1) ? N1 : HD;
  const int e  = blockIdx.z;
  const int ne = cnt[e];
  const int m0 = blockIdx.y * 64;
  if (m0 >= ne) return;
  const int n0 = blockIdx.x * 32;
  const int lane = threadIdx.x;
  const int l15 = lane & 15, l4 = lane >> 4;

  const int* glist = (STAGE == 1 ? tok_list : pair_list) + e * NTOK;
  const int* plist = pair_list + e * NTOK;

  // A per-lane byte offsets into Asrc for 4 m-frags (row = gathered token/pair)
  const char* Abase = (const char*)Asrc;
  unsigned aofs[4];
#pragma unroll
  for (int f = 0; f < 4; ++f) {
    int slot = m0 + f * 16 + l15; if (slot > ne - 1) slot = ne - 1;
    aofs[f] = (unsigned)glist[slot] * (unsigned)(HD * 2) + (unsigned)(l4 * 16);
  }
  // B per-lane offsets (int units) for 2 n-frags; row = n0 + f*16 + l15 (no guard: NDIM%32==0)
  unsigned bofs[2], sofs[2];
#pragma unroll
  for (int f = 0; f < 2; ++f) {
    int row = n0 + f * 16 + l15;
    unsigned rb = (unsigned)(e * NDIM + row) * NGRP;
    bofs[f] = rb * 16 + (unsigned)(l4 * 4);   // + (t*2+kk)*16
    sofs[f] = rb;                             // + t*2+kk
  }

  f32x4 zero = {0.f, 0.f, 0.f, 0.f};
  f32x4 acc[4][2];
#pragma unroll
  for (int a = 0; a < 4; ++a)
#pragma unroll
    for (int b = 0; b < 2; ++b) acc[a][b] = zero;

  // B raw fragments for current tile: q[nf][kk] + scale
  i32x4 q00, q01, q10, q11; int s00, s01, s10, s11;
  q00 = *(const i32x4*)(Bblk + bofs[0] + 0 * 16);  s00 = Bscl[sofs[0] + 0];
  q01 = *(const i32x4*)(Bblk + bofs[0] + 1 * 16);  s01 = Bscl[sofs[0] + 1];
  q10 = *(const i32x4*)(Bblk + bofs[1] + 0 * 16);  s10 = Bscl[sofs[1] + 0];
  q11 = *(const i32x4*)(Bblk + bofs[1] + 1 * 16);  s11 = Bscl[sofs[1] + 1];

  for (int t = 0; t < NKT; ++t) {
    // prefetch B(t+1) (wrap on last iter; redundant L2-hit load, keeps code uniform)
    const int tn = (t + 1 == NKT) ? 0 : t + 1;
    i32x4 p00 = *(const i32x4*)(Bblk + bofs[0] + (unsigned)(tn * 2 + 0) * 16);
    i32x4 p01 = *(const i32x4*)(Bblk + bofs[0] + (unsigned)(tn * 2 + 1) * 16);
    i32x4 p10 = *(const i32x4*)(Bblk + bofs[1] + (unsigned)(tn * 2 + 0) * 16);
    i32x4 p11 = *(const i32x4*)(Bblk + bofs[1] + (unsigned)(tn * 2 + 1) * 16);
    int   t00 = Bscl[sofs[0] + tn * 2];
    int   t01 = Bscl[sofs[0] + tn * 2 + 1];
    int   t10 = Bscl[sofs[1] + tn * 2];
    int   t11 = Bscl[sofs[1] + tn * 2 + 1];

    // A fragments for tile t (L2-resident activations)
    i32x4 a[4][2];
#pragma unroll
    for (int f = 0; f < 4; ++f) {
#pragma unroll
      for (int kk = 0; kk < 2; ++kk)
        a[f][kk] = *(const i32x4*)(Abase + aofs[f] + (unsigned)(t * 128 + kk * 64));
    }

    // dequant current B tiles
    short8 b00 = dq_frag(q00, s00);
    short8 b01 = dq_frag(q01, s01);
    short8 b10 = dq_frag(q10, s10);
    short8 b11 = dq_frag(q11, s11);

    // MFMA: acc[mf][nf] += A[mf][kk] * B[nf][kk]
#pragma unroll
    for (int kk = 0; kk < 2; ++kk) {
      short8 bk0 = kk ? b01 : b00;
      short8 bk1 = kk ? b11 : b10;
#pragma unroll
      for (int mf = 0; mf < 4; ++mf) {
        short8 af = __builtin_bit_cast(short8, a[mf][kk]);
        acc[mf][0] = __builtin_amdgcn_mfma_f32_16x16x32_bf16(af, bk0, acc[mf][0], 0, 0, 0);
        acc[mf][1] = __builtin_amdgcn_mfma_f32_16x16x32_bf16(af, bk1, acc[mf][1], 0, 0, 0);
      }
    }

    // rotate prefetched B into current
    q00 = p00; q01 = p01; q10 = p10; q11 = p11;
    s00 = t00; s01 = t01; s10 = t10; s11 = t11;
  }

  // --- epilogue ---
  if (STAGE == 1) {
#pragma unroll
    for (int ma = 0; ma < 4; ++ma) {
#pragma unroll
      for (int nb = 0; nb < 2; ++nb) {
        int ncol = n0 + nb * 16 + l15;
        float bias = Bbias[e * NDIM + ncol];
#pragma unroll
        for (int j = 0; j < 4; ++j) {
          float u  = acc[ma][nb][j] + bias;
          float up = __shfl_xor(u, 1);
          int slot = m0 + ma * 16 + l4 * 4 + j;
          if (!(lane & 1) && slot < ne) {
            float g  = fminf(u, 7.f);
            float lv = fminf(fmaxf(up, -7.f), 7.f);
            float hv = g / (1.f + __expf(-1.702f * g)) * (lv + 1.f);
            h_out[(size_t)plist[slot] * ID + (ncol >> 1)] = __float2bfloat16(hv);
          }
        }
      }
    }
  } else {
#pragma unroll
    for (int ma = 0; ma < 4; ++ma) {
#pragma unroll
      for (int nb = 0; nb < 2; ++nb) {
        int ncol = n0 + nb * 16 + l15;
        float bias = Bbias[e * NDIM + ncol];
#pragma unroll
        for (int j = 0; j < 4; ++j) {
          int slot = m0 + ma * 16 + l4 * 4 + j;
          if (slot < ne)
            o_out[(size_t)plist[slot] * HD + ncol] = acc[ma][nb][j] + bias;
        }
      }
    }
  }
}

// ---------------- Final combine ----------------
__global__ __launch_bounds__(256)
void final_k(const float* __restrict__ x, const float* __restrict__ obuf,
             const float* __restrict__ wpair, float* __restrict__ out)
{
  int t = blockIdx.x;
  float w0 = wpair[t * 4 + 0], w1 = wpair[t * 4 + 1];
  float w2 = wpair[t * 4 + 2], w3 = wpair[t * 4 + 3];
  const float* o0 = obuf + (size_t)(t * 4) * HD;
  for (int i = threadIdx.x; i < HD; i += 256) {
    float r = x[(size_t)t * HD + i]
            + w0 * o0[i] + w1 * o0[HD + i] + w2 * o0[2 * HD + i] + w3 * o0[3 * HD + i];
    out[(size_t)t * HD + i] = r;
  }
}

extern "C" void kernel_launch(void* const* d_in, const int* in_sizes, int n_in,
                              void* d_out, int out_size, void* d_ws, size_t ws_size,
                              hipStream_t stream)
{
  const float* x    = (const float*)d_in[0];
  const float* nsc  = (const float*)d_in[1];
  const float* gw   = (const float*)d_in[2];
  const float* gb   = (const float*)d_in[3];
  const int*   b1   = (const int*)d_in[4];
  const int*   s1   = (const int*)d_in[5];
  const float* bia1 = (const float*)d_in[6];
  const int*   b2   = (const int*)d_in[7];
  const int*   s2   = (const int*)d_in[8];
  const float* bia2 = (const float*)d_in[9];
  float* out = (float*)d_out;

  char* ws = (char*)d_ws;
  size_t off = 0;
  auto alloc = [&](size_t bytes) {
    char* p = ws + off;
    off = (off + bytes + 255) & ~(size_t)255;
    return p;
  };
  float*           tf    = (float*)alloc((size_t)NTOK * HD * 4);
  __hip_bfloat16*  tb    = (__hip_bfloat16*)alloc((size_t)NTOK * HD * 2);
  __hip_bfloat16*  hbuf  = (__hip_bfloat16*)alloc((size_t)NTOK * TOPK * ID * 2);
  float*           obuf  = (float*)alloc((size_t)NTOK * TOPK * HD * 4);
  float*           wpair = (float*)alloc(NTOK * TOPK * 4);
  int*             cnt   = (int*)alloc(64);
  int*             tokl  = (int*)alloc(NEXP * NTOK * 4);
  int*             pairl = (int*)alloc(NEXP * NTOK * 4);

  rmsnorm_k<<<NTOK, 256, 0, stream>>>(x, nsc, tf, tb, cnt);
  router_k<<<NTOK, 256, 0, stream>>>(tf, gw, gb, wpair, cnt, tokl, pairl);
  moe_gemm<1><<<dim3(N1 / 32, 8, NEXP), 64, 0, stream>>>(tb, b1, s1, bia1, cnt, tokl, pairl, hbuf, nullptr);
  moe_gemm<2><<<dim3(HD / 32, 8, NEXP), 64, 0, stream>>>(hbuf, b2, s2, bia2, cnt, tokl, pairl, nullptr, obuf);
  final_k<<<NTOK, 256, 0, stream>>>(x, obuf, wpair, out);
}

// Round 7
// 511.008 us; speedup vs baseline: 1.5727x; 1.5727x over previous
//
#include <hip/hip_runtime.h>
#include <hip/hip_bf16.h>

typedef __attribute__((ext_vector_type(8))) short short8;
typedef __attribute__((ext_vector_type(4))) float f32x4;
typedef __attribute__((ext_vector_type(4))) int i32x4;
typedef __attribute__((ext_vector_type(4))) unsigned u32x4;

#define NTOK 512
#define NEXP 16
#define TOPK 4
#define HD   2880
#define ID   2880
#define N1   5760   // 2*I
#define NGRP 90     // 32-value groups per row
#define NKT  45     // HD/64 K-steps

// ---------------- async global->LDS (16B per lane) ----------------
__device__ __forceinline__ void async16(void* lds, const void* g) {
  __builtin_amdgcn_global_load_lds((const __attribute__((address_space(1))) unsigned*)g,
                                   (__attribute__((address_space(3))) unsigned*)lds,
                                   16, 0, 0);
}

__device__ __forceinline__ unsigned perm(unsigned hi, unsigned lo, unsigned sel) {
  return __builtin_amdgcn_perm(hi, lo, sel);
}

// ---------------- perm-LUT MXFP4 dequant (bit-exact bf16, scale folded) ----------------
__device__ __forceinline__ u32x4 dq_word4(unsigned p, unsigned hbl, unsigned hbh,
                                          unsigned lbl, unsigned lbh) {
  unsigned ph = p >> 4;
  unsigned il = p  & 0x07070707u, sl = p  & 0x08080808u;
  unsigned ih = ph & 0x07070707u, sh = ph & 0x08080808u;
  unsigned hbL = perm(hbh, hbl, il) | (sl << 4);
  unsigned lbL = perm(lbh, lbl, il);
  unsigned hbH = perm(hbh, hbl, ih) | (sh << 4);
  unsigned lbH = perm(lbh, lbl, ih);
  unsigned mL01 = perm(hbL, lbL, 0x05010400u);
  unsigned mL23 = perm(hbL, lbL, 0x07030602u);
  unsigned mH01 = perm(hbH, lbH, 0x05010400u);
  unsigned mH23 = perm(hbH, lbH, 0x07030602u);
  u32x4 w;
  w.x = perm(mH01, mL01, 0x05040100u);
  w.y = perm(mH01, mL01, 0x07060302u);
  w.z = perm(mH23, mL23, 0x05040100u);
  w.w = perm(mH23, mL23, 0x07060302u);
  return w;
}

// one B MFMA fragment: 4 widened nibble-bytes (8 values) + per-lane scale -> short8 bf16
__device__ __forceinline__ short8 dq_frag(i32x4 q, int sc) {
  unsigned m7 = (unsigned)((127 - sc) << 7);          // sc in [118,127]
  unsigned mm = m7 | (m7 << 16);
  unsigned e10 = (0x3F00u - m7) << 16;                // entry0 stays exact 0
  unsigned e32 = 0x3FC03F80u - mm;
  unsigned e54 = 0x40404000u - mm;
  unsigned e76 = 0x40C04080u - mm;
  unsigned hbl = perm(e32, e10, 0x07050301u);
  unsigned hbh = perm(e76, e54, 0x07050301u);
  unsigned lbl = perm(e32, e10, 0x06040200u);
  unsigned lbh = perm(e76, e54, 0x06040200u);
  unsigned pk = (unsigned)q.x | ((unsigned)q.y << 8) |
                ((unsigned)q.z << 16) | ((unsigned)q.w << 24);
  u32x4 w = dq_word4(pk, hbl, hbh, lbl, lbh);
  return __builtin_bit_cast(short8, w);
}

// ---------------- RMSNorm (also zeroes cnt; runs before router on the stream) ----------------
__global__ __launch_bounds__(256)
void rmsnorm_k(const float* __restrict__ x, const float* __restrict__ nsc,
               float* __restrict__ tf, __hip_bfloat16* __restrict__ tb,
               int* __restrict__ cnt)
{
  int t = blockIdx.x;
  if (t == 0 && threadIdx.x < NEXP) cnt[threadIdx.x] = 0;
  const float* xr = x + (size_t)t * HD;
  float s = 0.f;
  for (int i = threadIdx.x; i < HD; i += 256) { float v = xr[i]; s += v * v; }
#pragma unroll
  for (int o = 32; o > 0; o >>= 1) s += __shfl_down(s, o);
  __shared__ float red[4];
  if ((threadIdx.x & 63) == 0) red[threadIdx.x >> 6] = s;
  __syncthreads();
  float tot = red[0] + red[1] + red[2] + red[3];
  float rinv = rsqrtf(tot / (float)HD + 1e-5f);
  for (int i = threadIdx.x; i < HD; i += 256) {
    float v = xr[i] * rinv * nsc[i];
    tf[(size_t)t * HD + i] = v;
    tb[(size_t)t * HD + i] = __float2bfloat16(v);
  }
}

// ---------------- Router ----------------
__global__ __launch_bounds__(256)
void router_k(const float* __restrict__ tf, const float* __restrict__ gw,
              const float* __restrict__ gb, float* __restrict__ wpair,
              int* __restrict__ cnt, int* __restrict__ tok_list, int* __restrict__ pair_list)
{
  int t = blockIdx.x;
  int tid = threadIdx.x;
  int e = tid >> 4, l16 = tid & 15;
  const float* tr = tf + (size_t)t * HD;
  float s = 0.f;
  for (int i = l16; i < HD; i += 16) s += tr[i] * gw[e * HD + i];
#pragma unroll
  for (int o = 1; o < 16; o <<= 1) s += __shfl_xor(s, o);
  __shared__ float logits[NEXP];
  if (l16 == 0) logits[e] = s + gb[e];
  __syncthreads();
  if (tid == 0) {
    float v[NEXP];
#pragma unroll
    for (int i = 0; i < NEXP; ++i) v[i] = logits[i];
    int idx[TOPK]; float val[TOPK];
#pragma unroll
    for (int k = 0; k < TOPK; ++k) {
      int bi = 0; float bv = -1e30f;
      for (int i = 0; i < NEXP; ++i) if (v[i] > bv) { bv = v[i]; bi = i; }
      idx[k] = bi; val[k] = bv; v[bi] = -1e30f;
    }
    float mx = val[0], sum = 0.f, w[TOPK];
#pragma unroll
    for (int k = 0; k < TOPK; ++k) { w[k] = __expf(val[k] - mx); sum += w[k]; }
#pragma unroll
    for (int k = 0; k < TOPK; ++k) {
      float wk = w[k] / sum;
      int ee = idx[k];
      int slot = atomicAdd(&cnt[ee], 1);
      tok_list[ee * NTOK + slot]  = t;
      pair_list[ee * NTOK + slot] = t * TOPK + k;
      wpair[t * TOPK + k] = wk;
    }
  }
}

// ---------------- Grouped GEMM: hybrid. Tile 128M x 128N, 4 waves (each 128M x 32N).
// A: LDS double-buffer (32 KB total) via global_load_lds, XOR-swizzled, shared by block.
// B: per-wave direct global->fragment registers, perm-LUT dequant, depth-1 prefetch.
template<int STAGE>
__global__ __launch_bounds__(256, 3)
void moe_gemm(const __hip_bfloat16* __restrict__ Asrc,
              const int* __restrict__ Bblk, const int* __restrict__ Bscl,
              const float* __restrict__ Bbias,
              const int* __restrict__ cnt,
              const int* __restrict__ tok_list, const int* __restrict__ pair_list,
              __hip_bfloat16* __restrict__ h_out, float* __restrict__ o_out)
{
  constexpr int NDIM = (STAGE == 1) ? N1 : HD;
  const int e  = blockIdx.z;
  const int ne = cnt[e];
  const int m0 = blockIdx.y * 128;
  if (m0 >= ne) return;
  const int n0 = blockIdx.x * 128;
  const int tid = threadIdx.x;
  const int wave = tid >> 6, lane = tid & 63;
  const int l15 = lane & 15, l4 = lane >> 4;

  __shared__ __align__(16) char Abuf[2][16384];  // [128 rows][128 B] bf16, XOR-swizzled

  const int* glist = (STAGE == 1 ? tok_list : pair_list) + e * NTOK;
  const int* plist = pair_list + e * NTOK;

  // --- A staging bases (4 issues of 256 lanes x 16B = 16 KB per K-step) ---
  const char* agbase[4];
  int aldsoff[4];
#pragma unroll
  for (int i = 0; i < 4; ++i) {
    int o   = i * 4096 + tid * 16;
    int row = o >> 7;
    int scb = (o & 127) ^ ((row & 7) << 4);   // inverse-swizzled source chunk
    int slot = m0 + row; if (slot > ne - 1) slot = ne - 1;
    agbase[i]  = (const char*)Asrc + (size_t)glist[slot] * (HD * 2) + scb;
    aldsoff[i] = i * 4096 + wave * 1024;      // wave-uniform base; HW adds lane*16
  }

  // --- B per-lane offsets (int units): wave owns cols [n0+wave*32, +32), 2 n-frags ---
  const int wn = wave * 32;
  unsigned bofs[2], sofs[2];
#pragma unroll
  for (int f = 0; f < 2; ++f) {
    int row = n0 + wn + f * 16 + l15;
    if (row > NDIM - 1) row = NDIM - 1;       // stage-2 tail clamp (dup load, store guarded)
    unsigned rb = (unsigned)(e * NDIM + row) * NGRP;
    bofs[f] = rb * 16 + (unsigned)(l4 * 4);   // + (t*2+kk)*16 per K-step
    sofs[f] = rb;                             // + t*2+kk
  }

  // --- A fragment LDS read offsets (k-independent): 8 m-frags x 2 kk ---
  int aoff[8][2];
#pragma unroll
  for (int mf = 0; mf < 8; ++mf) {
    int row = mf * 16 + l15;
#pragma unroll
    for (int kk = 0; kk < 2; ++kk)
      aoff[mf][kk] = row * 128 + ((kk * 64 + l4 * 16) ^ ((row & 7) << 4));
  }

  f32x4 zero = {0.f, 0.f, 0.f, 0.f};
  f32x4 acc[8][2];
#pragma unroll
  for (int a = 0; a < 8; ++a)
#pragma unroll
    for (int b = 0; b < 2; ++b) acc[a][b] = zero;

  // --- B current-tile raw fragments + prologue ---
  i32x4 q00, q01, q10, q11; int s00, s01, s10, s11;
  q00 = *(const i32x4*)(Bblk + bofs[0] + 0 * 16);  s00 = Bscl[sofs[0] + 0];
  q01 = *(const i32x4*)(Bblk + bofs[0] + 1 * 16);  s01 = Bscl[sofs[0] + 1];
  q10 = *(const i32x4*)(Bblk + bofs[1] + 0 * 16);  s10 = Bscl[sofs[1] + 0];
  q11 = *(const i32x4*)(Bblk + bofs[1] + 1 * 16);  s11 = Bscl[sofs[1] + 1];
#pragma unroll
  for (int i = 0; i < 4; ++i) async16(Abuf[0] + aldsoff[i], agbase[i]);
  __syncthreads();   // A(0) staged; B(0) regs arrived (drain includes them)

  for (int t = 0; t < NKT; ++t) {
    const int cur = t & 1, nxt = cur ^ 1;
    i32x4 p00, p01, p10, p11; int t00, t01, t10, t11;
    if (t + 1 < NKT) {
      // issue A(t+1) -> other LDS buffer and B(t+1) -> regs; latency hides under MFMA
#pragma unroll
      for (int i = 0; i < 4; ++i) async16(Abuf[nxt] + aldsoff[i], agbase[i] + (t + 1) * 128);
      const unsigned g = (unsigned)((t + 1) * 2);
      p00 = *(const i32x4*)(Bblk + bofs[0] + (g + 0) * 16);
      p01 = *(const i32x4*)(Bblk + bofs[0] + (g + 1) * 16);
      p10 = *(const i32x4*)(Bblk + bofs[1] + (g + 0) * 16);
      p11 = *(const i32x4*)(Bblk + bofs[1] + (g + 1) * 16);
      t00 = Bscl[sofs[0] + g];
      t01 = Bscl[sofs[0] + g + 1];
      t10 = Bscl[sofs[1] + g];
      t11 = Bscl[sofs[1] + g + 1];
    }

    // dequant current B tiles (registers, no LDS)
    short8 b00 = dq_frag(q00, s00);
    short8 b01 = dq_frag(q01, s01);
    short8 b10 = dq_frag(q10, s10);
    short8 b11 = dq_frag(q11, s11);

    // MFMA over current A buffer
    const char* Ab = Abuf[cur];
    __builtin_amdgcn_s_setprio(1);
#pragma unroll
    for (int kk = 0; kk < 2; ++kk) {
      short8 bk0 = kk ? b01 : b00;
      short8 bk1 = kk ? b11 : b10;
#pragma unroll
      for (int mf = 0; mf < 8; ++mf) {
        short8 af = *(const short8*)(Ab + aoff[mf][kk]);
        acc[mf][0] = __builtin_amdgcn_mfma_f32_16x16x32_bf16(af, bk0, acc[mf][0], 0, 0, 0);
        acc[mf][1] = __builtin_amdgcn_mfma_f32_16x16x32_bf16(af, bk1, acc[mf][1], 0, 0, 0);
      }
    }
    __builtin_amdgcn_s_setprio(0);

    __syncthreads();   // drains A(t+1) staging (and B regs); safe buffer swap

    if (t + 1 < NKT) {
      q00 = p00; q01 = p01; q10 = p10; q11 = p11;
      s00 = t00; s01 = t01; s10 = t10; s11 = t11;
    }
  }

  // --- epilogue ---
  if (STAGE == 1) {
#pragma unroll
    for (int ma = 0; ma < 8; ++ma) {
#pragma unroll
      for (int nb = 0; nb < 2; ++nb) {
        int ncol = n0 + wn + nb * 16 + l15;
        float bias = Bbias[e * NDIM + ncol];
#pragma unroll
        for (int j = 0; j < 4; ++j) {
          float u  = acc[ma][nb][j] + bias;
          float up = __shfl_xor(u, 1);
          int slot = m0 + ma * 16 + l4 * 4 + j;
          if (!(lane & 1) && slot < ne) {
            float g  = fminf(u, 7.f);
            float lv = fminf(fmaxf(up, -7.f), 7.f);
            float hv = g / (1.f + __expf(-1.702f * g)) * (lv + 1.f);
            h_out[(size_t)plist[slot] * ID + (ncol >> 1)] = __float2bfloat16(hv);
          }
        }
      }
    }
  } else {
#pragma unroll
    for (int ma = 0; ma < 8; ++ma) {
#pragma unroll
      for (int nb = 0; nb < 2; ++nb) {
        int ncol = n0 + wn + nb * 16 + l15;
        if (ncol < NDIM) {
          float bias = Bbias[e * NDIM + ncol];
#pragma unroll
          for (int j = 0; j < 4; ++j) {
            int slot = m0 + ma * 16 + l4 * 4 + j;
            if (slot < ne)
              o_out[(size_t)plist[slot] * HD + ncol] = acc[ma][nb][j] + bias;
          }
        }
      }
    }
  }
}

// ---------------- Final combine ----------------
__global__ __launch_bounds__(256)
void final_k(const float* __restrict__ x, const float* __restrict__ obuf,
             const float* __restrict__ wpair, float* __restrict__ out)
{
  int t = blockIdx.x;
  float w0 = wpair[t * 4 + 0], w1 = wpair[t * 4 + 1];
  float w2 = wpair[t * 4 + 2], w3 = wpair[t * 4 + 3];
  const float* o0 = obuf + (size_t)(t * 4) * HD;
  for (int i = threadIdx.x; i < HD; i += 256) {
    float r = x[(size_t)t * HD + i]
            + w0 * o0[i] + w1 * o0[HD + i] + w2 * o0[2 * HD + i] + w3 * o0[3 * HD + i];
    out[(size_t)t * HD + i] = r;
  }
}

extern "C" void kernel_launch(void* const* d_in, const int* in_sizes, int n_in,
                              void* d_out, int out_size, void* d_ws, size_t ws_size,
                              hipStream_t stream)
{
  const float* x    = (const float*)d_in[0];
  const float* nsc  = (const float*)d_in[1];
  const float* gw   = (const float*)d_in[2];
  const float* gb   = (const float*)d_in[3];
  const int*   b1   = (const int*)d_in[4];
  const int*   s1   = (const int*)d_in[5];
  const float* bia1 = (const float*)d_in[6];
  const int*   b2   = (const int*)d_in[7];
  const int*   s2   = (const int*)d_in[8];
  const float* bia2 = (const float*)d_in[9];
  float* out = (float*)d_out;

  char* ws = (char*)d_ws;
  size_t off = 0;
  auto alloc = [&](size_t bytes) {
    char* p = ws + off;
    off = (off + bytes + 255) & ~(size_t)255;
    return p;
  };
  float*           tf    = (float*)alloc((size_t)NTOK * HD * 4);
  __hip_bfloat16*  tb    = (__hip_bfloat16*)alloc((size_t)NTOK * HD * 2);
  __hip_bfloat16*  hbuf  = (__hip_bfloat16*)alloc((size_t)NTOK * TOPK * ID * 2);
  float*           obuf  = (float*)alloc((size_t)NTOK * TOPK * HD * 4);
  float*           wpair = (float*)alloc(NTOK * TOPK * 4);
  int*             cnt   = (int*)alloc(64);
  int*             tokl  = (int*)alloc(NEXP * NTOK * 4);
  int*             pairl = (int*)alloc(NEXP * NTOK * 4);

  rmsnorm_k<<<NTOK, 256, 0, stream>>>(x, nsc, tf, tb, cnt);
  router_k<<<NTOK, 256, 0, stream>>>(tf, gw, gb, wpair, cnt, tokl, pairl);
  moe_gemm<1><<<dim3(N1 / 128, 4, NEXP), 256, 0, stream>>>(tb, b1, s1, bia1, cnt, tokl, pairl, hbuf, nullptr);
  moe_gemm<2><<<dim3((HD + 127) / 128, 4, NEXP), 256, 0, stream>>>(hbuf, b2, s2, bia2, cnt, tokl, pairl, nullptr, obuf);
  final_k<<<NTOK, 256, 0, stream>>>(x, obuf, wpair, out);
}